// Round 7
// baseline (2099.316 us; speedup 1.0000x reference)
//
#include <hip/hip_runtime.h>
#include <hip/hip_bf16.h>
#include <math.h>

#define DD 768
#define HH 384
#define BB 16
#define TT 1024
#define NIH 1152

typedef __attribute__((ext_vector_type(8))) short short8;
typedef __attribute__((ext_vector_type(8))) __bf16 bf16x8;
typedef __attribute__((ext_vector_type(4))) float f32x4;

static __device__ __forceinline__ unsigned short f2bf(float f) {
  unsigned u = __float_as_uint(f);
  u += 0x7fffu + ((u >> 16) & 1u);          // RNE
  return (unsigned short)(u >> 16);
}
static __device__ __forceinline__ float bf2f(unsigned short h) {
  return __uint_as_float(((unsigned)h) << 16);
}
// f32 -> OCP e4m3fn (RNE, no inf; caller guarantees |x| <= 448)
static __device__ __forceinline__ unsigned char f2fp8(float x) {
  unsigned sgn = (__float_as_uint(x) >> 24) & 0x80u;
  float ax = fminf(fabsf(x), 448.f);
  unsigned code;
  if (ax < 0.015625f) {                     // subnormal: quantum 2^-9
    code = (unsigned)rintf(ax * 512.f);     // 0..8 (8 = min normal, natural carry)
  } else {
    unsigned b = __float_as_uint(ax);
    b += 0x7FFFFu + ((b >> 20) & 1u);       // RNE at mantissa bit 20
    code = (((b >> 23) - 120u) << 3) | ((b >> 20) & 7u);  // e=E-127+7 in [1,15]
  }
  return (unsigned char)(sgn | code);
}

// ---------------- k1a: weight conversion (wgw, wih -> bf16) ----------------
__global__ void prep_convert(const float* __restrict__ wgw, const float* __restrict__ wih,
                             unsigned short* __restrict__ wgw_bf, unsigned short* __restrict__ wih_bf)
{
  const int n1 = DD*DD, n2 = NIH*DD;
  int stride = gridDim.x * 256;
  for (int idx = blockIdx.x*256 + threadIdx.x; idx < n1+n2; idx += stride) {
    if (idx < n1) wgw_bf[idx]    = f2bf(wgw[idx]);
    else          wih_bf[idx-n1] = f2bf(wih[idx-n1]);
  }
}

// ---------------- k1c: Whh -> fp8 with per-row scale ----------------
__global__ __launch_bounds__(64) void prep_whh8(const float* __restrict__ whh,
    unsigned char* __restrict__ w8, float* __restrict__ dq)
{
  int r = blockIdx.x, l = threadIdx.x;
  const float* row = whh + (size_t)r*HH;
  float mx = 0.f;
  for (int i = l; i < HH; i += 64) mx = fmaxf(mx, fabsf(row[i]));
  for (int off = 32; off; off >>= 1) mx = fmaxf(mx, __shfl_down(mx, off));
  mx = __shfl(mx, 0);
  float sc = (mx > 0.f) ? 448.f/mx : 1.f;
  for (int i = l; i < HH; i += 64) w8[(size_t)r*HH + i] = f2fp8(row[i]*sc);
  if (l == 0) dq[r] = ((mx > 0.f) ? mx/448.f : 1.f) * (1.f/256.f);  // undo row scale and h scale
}

// ---------------- k1b: vL = Wg_w^T aL, vR = Wg_w^T aR, c0/c1 ----------------
__global__ void prep_vecs(const float* __restrict__ wgw, const float* __restrict__ wgb,
                          const float* __restrict__ aL, const float* __restrict__ aR,
                          float* __restrict__ vLR, float* __restrict__ c01)
{
  int tid = threadIdx.x;
  if (blockIdx.x < 3) {
    int j = blockIdx.x*256 + tid;   // 0..767
    float al = 0.f, ar = 0.f;
    for (int i = 0; i < DD; ++i) { float wv = wgw[i*DD + j]; al += wv*aL[i]; ar += wv*aR[i]; }
    vLR[j] = al; vLR[DD + j] = ar;
  } else {
    float al = 0.f, ar = 0.f;
    for (int i = tid; i < DD; i += 256) { float bv = wgb[i]; al += bv*aL[i]; ar += bv*aR[i]; }
    for (int off = 32; off; off >>= 1) { al += __shfl_down(al, off); ar += __shfl_down(ar, off); }
    __shared__ float red[8];
    int w = tid >> 6, l = tid & 63;
    if (l == 0) { red[w*2] = al; red[w*2+1] = ar; }
    __syncthreads();
    if (tid == 0) { c01[0] = red[0]+red[2]+red[4]+red[6]; c01[1] = red[1]+red[3]+red[5]+red[7]; }
  }
}

// ---------------- k2: exact f32 attention scores ----------------
__global__ __launch_bounds__(256) void scores_cvt(const float* __restrict__ emb,
    const float* __restrict__ vLR, const float* __restrict__ c01,
    float* __restrict__ ss, float* __restrict__ sr)
{
  int row = blockIdx.x, tid = threadIdx.x;
  const float* er = emb + (size_t)row*DD;
  float al = 0.f, ar = 0.f;
  for (int d = tid; d < DD; d += 256) {
    float e = er[d];
    al += e*vLR[d]; ar += e*vLR[DD+d];
  }
  for (int off = 32; off; off >>= 1) { al += __shfl_down(al, off); ar += __shfl_down(ar, off); }
  __shared__ float red[8];
  int w = tid >> 6, l = tid & 63;
  if (l == 0) { red[w*2] = al; red[w*2+1] = ar; }
  __syncthreads();
  if (tid == 0) {
    ss[row] = red[0]+red[2]+red[4]+red[6] + c01[0];
    sr[row] = red[1]+red[3]+red[5]+red[7] + c01[1];
  }
}

// ---------------- GEMM: C[m,n] = sum_k A[m,k]*Bw[n,k] + bias[n] ----------------
template<bool AF32>
__global__ __launch_bounds__(256) void gemm_bt(const void* __restrict__ Av,
    const unsigned short* __restrict__ Bw, const float* __restrict__ bias,
    unsigned short* __restrict__ C, int N, int MT, int Mreal)
{
  __shared__ __align__(16) unsigned short As[128][32];
  __shared__ __align__(16) unsigned short Bs[128][32];
  int tid = threadIdx.x;
  int tm = blockIdx.x % MT, tn = blockIdx.x / MT;
  int l = tid & 63, lr = l & 15, lk = l >> 4;
  int w = tid >> 6;
  int wm = (w >> 1)*64, wn = (w & 1)*64;
  f32x4 acc[4][4] = {};

  int c0 = tid, c1 = tid + 256;            // 512 16B-chunks per tile
  int r0 = c0 >> 2, ch0 = c0 & 3;
  int r1 = c1 >> 2, ch1 = c1 & 3;
  const unsigned short* Bbase = Bw + (size_t)tn*128*DD;

  for (int kt = 0; kt < 24; ++kt) {
    short8 va0, va1;
    if constexpr (AF32) {
      const float* Af = (const float*)Av + (size_t)tm*128*DD;
      f32x4 a0l = *(const f32x4*)(Af + r0*DD + kt*32 + ch0*8);
      f32x4 a0h = *(const f32x4*)(Af + r0*DD + kt*32 + ch0*8 + 4);
      f32x4 a1l = *(const f32x4*)(Af + r1*DD + kt*32 + ch1*8);
      f32x4 a1h = *(const f32x4*)(Af + r1*DD + kt*32 + ch1*8 + 4);
      #pragma unroll
      for (int j = 0; j < 4; ++j) {
        va0[j] = (short)f2bf(a0l[j]); va0[4+j] = (short)f2bf(a0h[j]);
        va1[j] = (short)f2bf(a1l[j]); va1[4+j] = (short)f2bf(a1h[j]);
      }
    } else {
      const unsigned short* Ab = (const unsigned short*)Av + (size_t)tm*128*DD;
      va0 = *(const short8*)(Ab + r0*DD + kt*32 + ch0*8);
      va1 = *(const short8*)(Ab + r1*DD + kt*32 + ch1*8);
    }
    short8 vb0 = *(const short8*)(Bbase + r0*DD + kt*32 + ch0*8);
    short8 vb1 = *(const short8*)(Bbase + r1*DD + kt*32 + ch1*8);
    __syncthreads();                        // previous compute done
    *(short8*)&As[r0][(ch0 ^ (r0&3))*8] = va0;
    *(short8*)&As[r1][(ch1 ^ (r1&3))*8] = va1;
    *(short8*)&Bs[r0][(ch0 ^ (r0&3))*8] = vb0;
    *(short8*)&Bs[r1][(ch1 ^ (r1&3))*8] = vb1;
    __syncthreads();
    bf16x8 af[4], bfr[4];
    #pragma unroll
    for (int mi = 0; mi < 4; ++mi) {
      int r = wm + mi*16 + lr;
      af[mi] = __builtin_bit_cast(bf16x8, *(const short8*)&As[r][(lk ^ (lr&3))*8]);
    }
    #pragma unroll
    for (int ni = 0; ni < 4; ++ni) {
      int r = wn + ni*16 + lr;
      bfr[ni] = __builtin_bit_cast(bf16x8, *(const short8*)&Bs[r][(lk ^ (lr&3))*8]);
    }
    #pragma unroll
    for (int mi = 0; mi < 4; ++mi)
      #pragma unroll
      for (int ni = 0; ni < 4; ++ni)
        acc[mi][ni] = __builtin_amdgcn_mfma_f32_16x16x32_bf16(af[mi], bfr[ni], acc[mi][ni], 0, 0, 0);
  }
  // epilogue: D layout col=lane&15, row=(lane>>4)*4+reg
  for (int mi = 0; mi < 4; ++mi) {
    int rbase = tm*128 + wm + mi*16 + lk*4;
    for (int ni = 0; ni < 4; ++ni) {
      int col = tn*128 + wn + ni*16 + lr;
      float bv = bias[col];
      #pragma unroll
      for (int jr = 0; jr < 4; ++jr) {
        int row = rbase + jr;
        if (row < Mreal) C[(size_t)row*N + col] = f2bf(acc[mi][ni][jr] + bv);
      }
    }
  }
}

// ---------------- k4: GAT attention (exact f32 scores) + build G_W (bf16) ----------------
__global__ __launch_bounds__(256) void gat_attn(const float* __restrict__ emb,
    const float* __restrict__ cls, const unsigned short* __restrict__ wgt_bf,
    const float* __restrict__ ss, const float* __restrict__ sr,
    const int* __restrict__ cidx, const int* __restrict__ cmask,
    unsigned short* __restrict__ gw_bf)
{
  int bx = blockIdx.x, tid = threadIdx.x;
  if (bx >= BB*TT) {                       // CLS rows
    int b = bx - BB*TT;
    unsigned short* dst = gw_bf + (size_t)(b*(TT+1))*DD;
    for (int d = tid; d < DD; d += 256) dst[d] = f2bf(cls[d]);
    return;
  }
  int b = bx >> 10, t = bx & 1023;
  __shared__ float sw[8];
  __shared__ int   si[8];
  __shared__ int   sm[8];
  if (tid < 8) {
    int ci = cidx[(size_t)bx*8 + tid];
    int cm = cmask[(size_t)bx*8 + tid];
    float s = ss[bx] + sr[(b<<10) + ci];
    s = s > 0.f ? s : 0.2f*s;              // leaky_relu(0.2)
    sw[tid] = cm ? s : -1e9f;
    si[tid] = ci;
    sm[tid] = cm;
  }
  __syncthreads();
  float a[8];
  float mx = -1e30f;
  #pragma unroll
  for (int k = 0; k < 8; ++k) mx = fmaxf(mx, sw[k]);
  float sum = 0.f;
  #pragma unroll
  for (int k = 0; k < 8; ++k) { a[k] = expf(sw[k]-mx); sum += a[k]; }
  float inv = 1.f/sum;
  #pragma unroll
  for (int k = 0; k < 8; ++k) a[k] = sm[k] ? a[k]*inv : 0.f;
  const float* er = emb + (size_t)bx*DD;
  unsigned short* dst = gw_bf + (size_t)(b*(TT+1) + t + 1)*DD;
  for (int d = tid; d < DD; d += 256) {
    float acc = er[d];
    #pragma unroll
    for (int k = 0; k < 8; ++k)
      if (a[k] != 0.f) acc += a[k]*bf2f(wgt_bf[((size_t)(b<<10) + si[k])*DD + d]);
    dst[d] = f2bf(acc);
  }
}

// ---------------- k6: GRU scan v5 — ONE workgroup per batch, Whh fp8 in VGPRs ----------------
// 512 threads / 8 waves per CU; wave w holds rowgroups w*9..w*9+8 (rows *16) of the
// 1152x384 fp8 Whh as MFMA A-fragments (216 VGPRs). h is quantized to fp8 (x256)
// each step in LDS; B frags are broadcast ds_reads. Zero inter-WG communication.
__global__ __launch_bounds__(512, 2) void gru_scan(const unsigned char* __restrict__ w8,
    const float* __restrict__ dq, const float* __restrict__ bhh,
    const unsigned short* __restrict__ xp, const int* __restrict__ clue,
    float* __restrict__ hfinal)
{
  __shared__ __align__(8) unsigned char h8[HH];
  __shared__ float y_s[NIH];
  __shared__ float bhh_s[NIH];
  __shared__ float dq_s[NIH];
  __shared__ unsigned char m_s[TT+1];
  int tid = threadIdx.x;
  int b = blockIdx.x;
  int w = tid >> 6, l = tid & 63, lr = l & 15, lk = l >> 4;

  // A fragments: lane holds row (rowgroup*16 + lr), bytes k = c*32 + lk*8 .. +8
  long areg[9][12];
  #pragma unroll
  for (int i = 0; i < 9; ++i) {
    int row = (w*9 + i)*16 + lr;
    const unsigned char* src = w8 + (size_t)row*HH;
    #pragma unroll
    for (int c = 0; c < 12; ++c)
      areg[i][c] = *(const long*)(src + c*32 + lk*8);
  }
  for (int i = tid; i < NIH; i += 512) { bhh_s[i] = bhh[i]; dq_s[i] = dq[i]; }
  for (int i = tid; i < HH; i += 512) h8[i] = 0;
  for (int t = tid; t < TT; t += 512) m_s[t+1] = (clue[b*TT + t] != 0) ? 1 : 0;
  if (tid == 0) m_s[0] = 1;
  __syncthreads();

  float h_prev = 0.f;                       // thread tid<384 owns h element tid
  for (int t = 0; t <= TT; ++t) {
    if (!m_s[t]) continue;                  // masked step: h unchanged, skip entirely
    float xr = 0.f, xz = 0.f, xn = 0.f;
    if (tid < HH) {                         // x_proj prefetch (consumed after barrier)
      const unsigned short* xrow = xp + (size_t)(b*(TT+1) + t)*NIH;
      xr = bf2f(xrow[tid]); xz = bf2f(xrow[HH + tid]); xn = bf2f(xrow[2*HH + tid]);
    }
    // MFMA: 3 batches of 3 rowgroups; B frags reloaded per quarter (regs: 216A+6B+12acc)
    #pragma unroll
    for (int bb = 0; bb < 3; ++bb) {
      f32x4 a0 = {}, a1 = {}, a2 = {};
      #pragma unroll
      for (int q = 0; q < 4; ++q) {
        long b0 = *(const long*)&h8[(q*3+0)*32 + lk*8];
        long b1 = *(const long*)&h8[(q*3+1)*32 + lk*8];
        long b2 = *(const long*)&h8[(q*3+2)*32 + lk*8];
        a0 = __builtin_amdgcn_mfma_f32_16x16x32_fp8_fp8(areg[bb*3+0][q*3+0], b0, a0, 0,0,0);
        a1 = __builtin_amdgcn_mfma_f32_16x16x32_fp8_fp8(areg[bb*3+1][q*3+0], b0, a1, 0,0,0);
        a2 = __builtin_amdgcn_mfma_f32_16x16x32_fp8_fp8(areg[bb*3+2][q*3+0], b0, a2, 0,0,0);
        a0 = __builtin_amdgcn_mfma_f32_16x16x32_fp8_fp8(areg[bb*3+0][q*3+1], b1, a0, 0,0,0);
        a1 = __builtin_amdgcn_mfma_f32_16x16x32_fp8_fp8(areg[bb*3+1][q*3+1], b1, a1, 0,0,0);
        a2 = __builtin_amdgcn_mfma_f32_16x16x32_fp8_fp8(areg[bb*3+2][q*3+1], b1, a2, 0,0,0);
        a0 = __builtin_amdgcn_mfma_f32_16x16x32_fp8_fp8(areg[bb*3+0][q*3+2], b2, a0, 0,0,0);
        a1 = __builtin_amdgcn_mfma_f32_16x16x32_fp8_fp8(areg[bb*3+1][q*3+2], b2, a1, 0,0,0);
        a2 = __builtin_amdgcn_mfma_f32_16x16x32_fp8_fp8(areg[bb*3+2][q*3+2], b2, a2, 0,0,0);
      }
      if (lr == 0) {                        // C layout: col=lane&15 (take col 0), row=lk*4+reg
        int r0b = (w*9 + bb*3 + 0)*16 + lk*4;
        int r1b = (w*9 + bb*3 + 1)*16 + lk*4;
        int r2b = (w*9 + bb*3 + 2)*16 + lk*4;
        #pragma unroll
        for (int j = 0; j < 4; ++j) {
          y_s[r0b+j] = a0[j]*dq_s[r0b+j];
          y_s[r1b+j] = a1[j]*dq_s[r1b+j];
          y_s[r2b+j] = a2[j]*dq_s[r2b+j];
        }
      }
    }
    __syncthreads();                        // y ready; all h8 reads done
    if (tid < HH) {
      float hr = y_s[tid]        + bhh_s[tid];
      float hz = y_s[HH + tid]   + bhh_s[HH + tid];
      float hn = y_s[2*HH + tid] + bhh_s[2*HH + tid];
      float rg = 1.f/(1.f + __expf(-(xr + hr)));
      float zg = 1.f/(1.f + __expf(-(xz + hz)));
      float a  = xn + rg*hn;
      a = fminf(fmaxf(a, -15.f), 15.f);
      float e2 = __expf(-2.f*a);
      float ng = (1.f - e2)/(1.f + e2);
      h_prev = (1.f - zg)*ng + zg*h_prev;
      h8[tid] = f2fp8(h_prev * 256.f);      // publish for next step's B frags
    }
    __syncthreads();
  }
  if (tid < HH) hfinal[b*HH + tid] = h_prev;   // exact f32
}

// ---------------- k6b: per-batch head contribution of h_clue ----------------
__global__ __launch_bounds__(384) void hpart_k(const float* __restrict__ hfinal,
    const float* __restrict__ Wc, const float* __restrict__ Wcb,
    const float* __restrict__ We, const float* __restrict__ Web, float* __restrict__ hpart)
{
  int b = blockIdx.x, tid = threadIdx.x;
  int j = tid >> 6, l = tid & 63;
  const float* wr = ((j < 3) ? (Wc + j*NIH) : (We + (j-3)*NIH)) + DD;
  float acc = 0.f;
  #pragma unroll
  for (int i = 0; i < 6; ++i) acc += hfinal[b*HH + l + i*64] * wr[l + i*64];
  for (int off = 32; off; off >>= 1) acc += __shfl_down(acc, off);
  if (l == 0) hpart[b*6 + j] = acc + ((j < 3) ? Wcb[j] : Web[j-3]);
}

// ---------------- k7: cause/effect heads ----------------
__global__ __launch_bounds__(256) void heads(const unsigned short* __restrict__ gw_bf,
    const float* __restrict__ Wc, const float* __restrict__ We,
    const float* __restrict__ hpart, float* __restrict__ out)
{
  __shared__ float Wl[6][DD];
  int tid = threadIdx.x;
  for (int idx = tid; idx < 6*DD; idx += 256) {
    int j = idx / DD, d = idx % DD;
    Wl[j][d] = (j < 3) ? Wc[j*NIH + d] : We[(j-3)*NIH + d];
  }
  __syncthreads();
  int w = tid >> 6, l = tid & 63;
  int row = blockIdx.x*4 + w;
  int b = row >> 10, t = row & 1023;
  const unsigned short* gr = gw_bf + (size_t)(b*(TT+1) + t + 1)*DD;
  float acc[6] = {0,0,0,0,0,0};
  for (int i = 0; i < 12; ++i) {
    int d = l + i*64;
    float v = bf2f(gr[d]);
    #pragma unroll
    for (int j = 0; j < 6; ++j) acc[j] += v * Wl[j][d];
  }
  #pragma unroll
  for (int j = 0; j < 6; ++j)
    for (int off = 32; off; off >>= 1) acc[j] += __shfl_down(acc[j], off);
  if (l == 0) {
    const float* hp = hpart + b*6;
    float* oc = out + (size_t)b*TT*3 + t*3;
    float* oe = out + (size_t)BB*TT*3 + (size_t)b*TT*3 + t*3;
    oc[0] = acc[0]+hp[0]; oc[1] = acc[1]+hp[1]; oc[2] = acc[2]+hp[2];
    oe[0] = acc[3]+hp[3]; oe[1] = acc[4]+hp[4]; oe[2] = acc[5]+hp[5];
  }
}

extern "C" void kernel_launch(void* const* d_in, const int* in_sizes, int n_in,
                              void* d_out, int out_size, void* d_ws, size_t ws_size,
                              hipStream_t stream)
{
  const float* emb  = (const float*)d_in[0];
  const float* cls  = (const float*)d_in[1];
  const float* wgw  = (const float*)d_in[2];
  const float* wgb  = (const float*)d_in[3];
  const float* aL   = (const float*)d_in[4];
  const float* aR   = (const float*)d_in[5];
  const float* wih  = (const float*)d_in[6];
  const float* bih  = (const float*)d_in[7];
  const float* whh  = (const float*)d_in[8];
  const float* bhh  = (const float*)d_in[9];
  const float* wcw  = (const float*)d_in[10];
  const float* wcb  = (const float*)d_in[11];
  const float* wew  = (const float*)d_in[12];
  const float* web  = (const float*)d_in[13];
  const int* cidx   = (const int*)d_in[14];
  const int* cmask  = (const int*)d_in[15];
  const int* clue   = (const int*)d_in[16];
  (void)in_sizes; (void)n_in; (void)out_size; (void)ws_size;

  char* ws = (char*)d_ws;
  size_t off = 0;
  auto alloc = [&](size_t bytes) { char* p = ws + off; off += (bytes + 255) & ~(size_t)255; return p; };
  // regionA: xp_bf (38MB); wgt_bf (25.2MB) aliases its head — disjoint lifetimes
  unsigned short* xp_bf  = (unsigned short*)alloc((size_t)16512*1152*2);
  unsigned short* wgt_bf = xp_bf;
  unsigned short* gw_bf  = (unsigned short*)alloc((size_t)16512*768*2);   // 129*128 rows padded
  unsigned short* wgw_bf = (unsigned short*)alloc((size_t)768*768*2);
  unsigned short* wih_bf = (unsigned short*)alloc((size_t)1152*768*2);
  unsigned char*  whh8   = (unsigned char*)alloc((size_t)1152*384);
  float* dq    = (float*)alloc(1152*4);
  float* vLR   = (float*)alloc(1536*4);
  float* c01   = (float*)alloc(256);
  float* ss    = (float*)alloc(16384*4);
  float* sr    = (float*)alloc(16384*4);
  float* hfin  = (float*)alloc((size_t)16*384*4);
  float* hpart = (float*)alloc(512);

  prep_convert<<<2048, 256, 0, stream>>>(wgw, wih, wgw_bf, wih_bf);
  prep_whh8<<<1152, 64, 0, stream>>>(whh, whh8, dq);
  prep_vecs<<<4, 256, 0, stream>>>(wgw, wgb, aL, aR, vLR, c01);
  scores_cvt<<<16384, 256, 0, stream>>>(emb, vLR, c01, ss, sr);
  gemm_bt<true><<<128*6, 256, 0, stream>>>(emb, wgw_bf, wgb, wgt_bf, 768, 128, 16384);
  gat_attn<<<16384+16, 256, 0, stream>>>(emb, cls, wgt_bf, ss, sr, cidx, cmask, gw_bf);
  gemm_bt<false><<<129*9, 256, 0, stream>>>(gw_bf, wih_bf, bih, xp_bf, 1152, 129, 16400);
  gru_scan<<<BB, 512, 0, stream>>>(whh8, dq, bhh, xp_bf, clue, hfin);
  hpart_k<<<16, 384, 0, stream>>>(hfin, wcw, wcb, wew, web, hpart);
  heads<<<4096, 256, 0, stream>>>(gw_bf, wcw, wew, hpart, (float*)d_out);
}